// Round 2
// baseline (1368.012 us; speedup 1.0000x reference)
//
#include <hip/hip_runtime.h>
#include <hip/hip_bf16.h>
#include <math.h>

typedef __bf16 bf16x8 __attribute__((ext_vector_type(8)));
typedef float  f32x4  __attribute__((ext_vector_type(4)));
typedef __hip_bfloat16 bf16_t;

static constexpr int C_    = 128;
static constexpr int L_    = 56 * 56;        // tokens per image
static constexpr int M_    = 64 * L_;        // 200704 total tokens
static constexpr int NWIN  = 64 * 64;        // 4096 windows
static constexpr int NC    = 8;              // chunks
static constexpr int MCH   = M_ / NC;        // 25088 rows per chunk
static constexpr int WCH   = NWIN / NC;      // 512 windows per chunk

// map windowed token index tw -> unwindowed token index (shift+window bijection)
__device__ inline long win_to_tok(int tw)
{
    int win = tw / 49, n = tw % 49;
    int bb  = win >> 6, wi = win & 63;
    int wh  = wi >> 3, wwp = wi & 7;
    int hs  = wh * 7 + n / 7;
    int wsv = wwp * 7 + n % 7;
    int hh  = (hs + 3) % 56;          // un-shift
    int ww  = (wsv + 3) % 56;
    return (long)bb * L_ + hh * 56 + ww;
}

__global__ void sentinel_kernel(float* o) { o[threadIdx.x] = 1e9f; }

// ---------------------------------------------------------------------------
// Transpose + f32->bf16 convert weight (K x N) -> (N x K)
// ---------------------------------------------------------------------------
__global__ void transpose_w(const float* __restrict__ w, bf16_t* __restrict__ wt,
                            int K, int N)
{
    int i = blockIdx.x * 256 + threadIdx.x;
    if (i >= K * N) return;
    int k = i / N, n = i % N;
    wt[(long)n * K + k] = __float2bfloat16(w[i]);
}

// ---------------------------------------------------------------------------
// GEMM: A (MCH x K bf16 row-major, or LN-fused source) @ Bt (N x K bf16) + bias
// One wave = 16-row strip across all N.  Block = 4 waves = 64 rows.
// LNM: 0 = A is plain bf16 (ptr Asrc)
//      1 = A = LN(gather shifted/windowed row from x f32)   [qkv]
//      2 = A = LN(y bf16 row, global row index)             [fc1]
// EPI: 0 = store bf16 chunk-local (qkv)
//      1 = window-reverse + unshift + add x residual -> y bf16 (proj)
//      2 = exact GELU -> bf16 chunk-local (fc1)
//      3 = + y residual -> f32 d_out at global rows (fc2)
// ---------------------------------------------------------------------------
template<int K, int N, int LNM, int EPI>
__global__ __launch_bounds__(256) void gemm_k(const void*  __restrict__ Asrc,
                                              const float* __restrict__ lng,
                                              const float* __restrict__ lnb,
                                              const bf16_t* __restrict__ Bt,
                                              const float*  __restrict__ bias,
                                              void*         __restrict__ outp,
                                              const float*  __restrict__ resx,
                                              const bf16_t* __restrict__ resy,
                                              int row_base)
{
    constexpr int NT = N / 16;
    int lane = threadIdx.x & 63;
    int wave = threadIdx.x >> 6;
    int la = lane & 15, lb = lane >> 4;
    int m0 = blockIdx.x * 64 + wave * 16;          // chunk-local row of strip

    // ---- A fragments ----
    bf16x8 af[K / 32];
    if constexpr (LNM == 0) {
        const bf16_t* arow = (const bf16_t*)Asrc + (long)(m0 + la) * K + lb * 8;
#pragma unroll
        for (int kt = 0; kt < K / 32; ++kt)
            af[kt] = *reinterpret_cast<const bf16x8*>(arow + kt * 32);
    } else {
        static_assert(LNM == 0 || K == 128, "LN fusion assumes K=128");
        float vals[4][8];
        float s = 0.f, q = 0.f;
        if constexpr (LNM == 1) {
            long src = win_to_tok(row_base + m0 + la);
            const float* xr = (const float*)Asrc + src * C_;
#pragma unroll
            for (int kt = 0; kt < 4; ++kt)
#pragma unroll
                for (int j = 0; j < 8; ++j) {
                    float v = xr[kt * 32 + lb * 8 + j];
                    vals[kt][j] = v; s += v; q += v * v;
                }
        } else {
            const bf16_t* yr = (const bf16_t*)Asrc + (long)(row_base + m0 + la) * C_;
#pragma unroll
            for (int kt = 0; kt < 4; ++kt) {
                bf16x8 v8 = *reinterpret_cast<const bf16x8*>(yr + kt * 32 + lb * 8);
#pragma unroll
                for (int j = 0; j < 8; ++j) {
                    float v = (float)v8[j];
                    vals[kt][j] = v; s += v; q += v * v;
                }
            }
        }
        // reduce across the 4 lanes sharing la (lane bits 4,5)
        s += __shfl_xor(s, 16); s += __shfl_xor(s, 32);
        q += __shfl_xor(q, 16); q += __shfl_xor(q, 32);
        float mean = s * (1.f / 128.f);
        float var  = q * (1.f / 128.f) - mean * mean;
        float rstd = rsqrtf(var + 1e-5f);
#pragma unroll
        for (int kt = 0; kt < 4; ++kt)
#pragma unroll
            for (int j = 0; j < 8; ++j) {
                int k = kt * 32 + lb * 8 + j;
                float xn = (vals[kt][j] - mean) * rstd * lng[k] + lnb[k];
                af[kt][j] = (__bf16)xn;
            }
    }

    // ---- accumulators (bias-initialized) ----
    f32x4 acc[NT];
#pragma unroll
    for (int nt = 0; nt < NT; ++nt) {
        float bv = bias[nt * 16 + la];
        acc[nt] = (f32x4){bv, bv, bv, bv};
    }

    // ---- MFMA main loop ----
#pragma unroll
    for (int kt = 0; kt < K / 32; ++kt) {
#pragma unroll
        for (int nt = 0; nt < NT; ++nt) {
            bf16x8 bfr = *reinterpret_cast<const bf16x8*>(
                Bt + (long)(nt * 16 + la) * K + kt * 32 + lb * 8);
            acc[nt] = __builtin_amdgcn_mfma_f32_16x16x32_bf16(af[kt], bfr, acc[nt], 0, 0, 0);
        }
    }

    // ---- epilogue ----
#pragma unroll
    for (int r = 0; r < 4; ++r) {
        int row = m0 + lb * 4 + r;                  // chunk-local
        if constexpr (EPI == 1) {
            long to = win_to_tok(row_base + row);
#pragma unroll
            for (int nt = 0; nt < NT; ++nt) {
                int col = nt * 16 + la;
                ((bf16_t*)outp)[to * C_ + col] =
                    __float2bfloat16(acc[nt][r] + resx[to * C_ + col]);
            }
        } else if constexpr (EPI == 3) {
            long gr = (long)(row_base + row);
#pragma unroll
            for (int nt = 0; nt < NT; ++nt) {
                int col = nt * 16 + la;
                ((float*)outp)[gr * N + col] =
                    acc[nt][r] + (float)resy[gr * N + col];
            }
        } else {
#pragma unroll
            for (int nt = 0; nt < NT; ++nt) {
                int col = nt * 16 + la;
                float v = acc[nt][r];
                if constexpr (EPI == 2)
                    v = 0.5f * v * (1.f + erff(v * 0.70710678118654752f));
                ((bf16_t*)outp)[(long)row * N + col] = __float2bfloat16(v);
            }
        }
    }
}

// ---------------------------------------------------------------------------
// Windowed attention: one block per window, one wave per head.
// K,V staged in LDS (f32). Lane n (<49) owns query row n entirely in regs.
// ---------------------------------------------------------------------------
__global__ __launch_bounds__(256) void attn_kernel(const bf16_t* __restrict__ qkv,
                                                   const float*  __restrict__ rpb,
                                                   bf16_t* __restrict__ out,
                                                   int win_base)
{
    int winl = blockIdx.x;
    int wing = win_base + winl;
    int h    = threadIdx.x >> 6;
    int lane = threadIdx.x & 63;

    __shared__ float kbuf[4][49][32];
    __shared__ float vbuf[4][49][32];

    const bf16_t* base = qkv + (long)winl * 49 * 384;

    for (int idx = lane; idx < 49 * 32; idx += 64) {
        int n = idx >> 5, d = idx & 31;
        kbuf[h][n][d] = __bfloat162float(base[n * 384 + 128 + h * 32 + d]);
        vbuf[h][n][d] = __bfloat162float(base[n * 384 + 256 + h * 32 + d]);
    }

    int n = lane < 49 ? lane : 48;
    f32x4 qv[8];
#pragma unroll
    for (int dq = 0; dq < 8; ++dq)
#pragma unroll
        for (int r = 0; r < 4; ++r)
            qv[dq][r] = __bfloat162float(base[n * 384 + h * 32 + dq * 4 + r]) *
                        0.17677669529663687f;   // 1/sqrt(32)

    __syncthreads();

    int wi  = wing & 63;
    int wh  = wi >> 3, wwp = wi & 7;
    int i1  = n / 7, j1 = n % 7;
    int hh1 = wh * 7 + i1, ww1 = wwp * 7 + j1;
    int rr1 = hh1 < 49 ? 0 : (hh1 < 53 ? 1 : 2);
    int rc1 = ww1 < 49 ? 0 : (ww1 < 53 ? 1 : 2);

    const f32x4* k4 = reinterpret_cast<const f32x4*>(&kbuf[h][0][0]);
    const f32x4* v4 = reinterpret_cast<const f32x4*>(&vbuf[h][0][0]);

    float S[49];
#pragma unroll
    for (int m = 0; m < 49; ++m) {
        f32x4 sv = (f32x4){0, 0, 0, 0};
#pragma unroll
        for (int dq = 0; dq < 8; ++dq)
            sv = k4[m * 8 + dq] * qv[dq] + sv;
        float s = sv[0] + sv[1] + sv[2] + sv[3];

        int i2 = m / 7, j2 = m % 7;
        s += rpb[((i1 - i2 + 6) * 13 + (j1 - j2 + 6)) * 4 + h];

        int hh2 = wh * 7 + i2, ww2 = wwp * 7 + j2;
        int rr2 = hh2 < 49 ? 0 : (hh2 < 53 ? 1 : 2);
        int rc2 = ww2 < 49 ? 0 : (ww2 < 53 ? 1 : 2);
        if (rr1 != rr2 || rc1 != rc2) s -= 100.f;
        S[m] = s;
    }

    float mx = -1e30f;
#pragma unroll
    for (int m = 0; m < 49; ++m) mx = fmaxf(mx, S[m]);
    float sum = 0.f;
#pragma unroll
    for (int m = 0; m < 49; ++m) { S[m] = __expf(S[m] - mx); sum += S[m]; }
    float inv = 1.f / sum;

    f32x4 o[8];
#pragma unroll
    for (int i = 0; i < 8; ++i) o[i] = (f32x4){0, 0, 0, 0};
#pragma unroll
    for (int m = 0; m < 49; ++m) {
        float pm = S[m] * inv;
#pragma unroll
        for (int dq = 0; dq < 8; ++dq)
            o[dq] = v4[m * 8 + dq] * pm + o[dq];
    }

    if (lane < 49) {
        bf16_t* orow = out + ((long)winl * 49 + lane) * C_ + h * 32;
#pragma unroll
        for (int dq = 0; dq < 8; ++dq)
#pragma unroll
            for (int r = 0; r < 4; ++r)
                orow[dq * 4 + r] = __float2bfloat16(o[dq][r]);
    }
}

// ---------------------------------------------------------------------------
extern "C" void kernel_launch(void* const* d_in, const int* in_sizes, int n_in,
                              void* d_out, int out_size, void* d_ws, size_t ws_size,
                              hipStream_t stream)
{
    (void)in_sizes; (void)n_in; (void)out_size;

    const float* x      = (const float*)d_in[0];
    const float* n1g    = (const float*)d_in[1];
    const float* n1b    = (const float*)d_in[2];
    const float* qkv_w  = (const float*)d_in[3];
    const float* qkv_b  = (const float*)d_in[4];
    const float* proj_w = (const float*)d_in[5];
    const float* proj_b = (const float*)d_in[6];
    const float* rpb    = (const float*)d_in[7];
    const float* n2g    = (const float*)d_in[8];
    const float* n2b    = (const float*)d_in[9];
    const float* fc1_w  = (const float*)d_in[10];
    const float* fc1_b  = (const float*)d_in[11];
    const float* fc2_w  = (const float*)d_in[12];
    const float* fc2_b  = (const float*)d_in[13];

    char*  ws  = (char*)d_ws;
    size_t off = 0;
    auto alloc = [&](size_t bytes) -> void* {
        void* p = ws + off;
        off += (bytes + 255) & ~(size_t)255;
        return p;
    };

    bf16_t* y        = (bf16_t*)alloc((size_t)M_ * C_ * 2);       // 51.4 MB
    char*   chunkbuf = (char*)  alloc((size_t)MCH * 512 * 2);     // 25.7 MB
    bf16_t* qkv_wt   = (bf16_t*)alloc(128 * 384 * 2);
    bf16_t* proj_wt  = (bf16_t*)alloc(128 * 128 * 2);
    bf16_t* fc1_wt   = (bf16_t*)alloc(128 * 512 * 2);
    bf16_t* fc2_wt   = (bf16_t*)alloc(512 * 128 * 2);

    if (off > ws_size) {                       // visible, diagnosable failure
        sentinel_kernel<<<1, 256, 0, stream>>>((float*)d_out);
        return;
    }

    bf16_t* qkvb = (bf16_t*)chunkbuf;                              // 19.3 MB
    bf16_t* attb = (bf16_t*)(chunkbuf + (size_t)MCH * 384 * 2);    //  6.4 MB
    bf16_t* h1   = (bf16_t*)chunkbuf;                              // 25.7 MB (MLP phase)

    transpose_w<<<(128 * 384 + 255) / 256, 256, 0, stream>>>(qkv_w, qkv_wt, 128, 384);
    transpose_w<<<(128 * 128 + 255) / 256, 256, 0, stream>>>(proj_w, proj_wt, 128, 128);
    transpose_w<<<(128 * 512 + 255) / 256, 256, 0, stream>>>(fc1_w, fc1_wt, 128, 512);
    transpose_w<<<(512 * 128 + 255) / 256, 256, 0, stream>>>(fc2_w, fc2_wt, 512, 128);

    // ---- attention path, chunked ----
    for (int c = 0; c < NC; ++c) {
        int rb = c * MCH, wb = c * WCH;
        // LN1(gather x) @ qkv_w -> qkvb (chunk-local, bf16)
        gemm_k<128, 384, 1, 0><<<MCH / 64, 256, 0, stream>>>(
            x, n1g, n1b, qkv_wt, qkv_b, qkvb, nullptr, nullptr, rb);
        // windowed attention -> attb
        attn_kernel<<<WCH, 256, 0, stream>>>(qkvb, rpb, attb, wb);
        // proj + window-reverse + x residual -> y (bf16, global token order)
        gemm_k<128, 128, 0, 1><<<MCH / 64, 256, 0, stream>>>(
            attb, nullptr, nullptr, proj_wt, proj_b, y, x, nullptr, rb);
    }

    // ---- MLP path, chunked ----
    for (int c = 0; c < NC; ++c) {
        int rb = c * MCH;
        // LN2(y) @ fc1_w + GELU -> h1 (chunk-local, bf16)
        gemm_k<128, 512, 2, 2><<<MCH / 64, 256, 0, stream>>>(
            y, n2g, n2b, fc1_wt, fc1_b, h1, nullptr, nullptr, rb);
        // h1 @ fc2_w + y residual -> d_out (f32, global rows)
        gemm_k<512, 128, 0, 3><<<MCH / 64, 256, 0, stream>>>(
            h1, nullptr, nullptr, fc2_wt, fc2_b, d_out, nullptr, y, rb);
    }
}

// Round 3
// 969.613 us; speedup vs baseline: 1.4109x; 1.4109x over previous
//
#include <hip/hip_runtime.h>
#include <hip/hip_bf16.h>
#include <math.h>

typedef __bf16 bf16x8 __attribute__((ext_vector_type(8)));
typedef float  f32x4  __attribute__((ext_vector_type(4)));
typedef __hip_bfloat16 bf16_t;

static constexpr int C_    = 128;
static constexpr int L_    = 56 * 56;        // tokens per image
static constexpr int M_    = 64 * L_;        // 200704 total tokens
static constexpr int NWIN  = 64 * 64;        // 4096 windows
static constexpr int NC    = 8;              // chunks
static constexpr int MCH   = M_ / NC;        // 25088 rows per chunk
static constexpr int WCH   = NWIN / NC;      // 512 windows per chunk

// map windowed token index tw -> unwindowed token index (shift+window bijection)
__device__ inline long win_to_tok(int tw)
{
    int win = tw / 49, n = tw % 49;
    int bb  = win >> 6, wi = win & 63;
    int wh  = wi >> 3, wwp = wi & 7;
    int hs  = wh * 7 + n / 7;
    int wsv = wwp * 7 + n % 7;
    int hh  = (hs + 3) % 56;          // un-shift
    int ww  = (wsv + 3) % 56;
    return (long)bb * L_ + hh * 56 + ww;
}

__global__ void sentinel_kernel(float* o) { o[threadIdx.x] = 1e9f; }

// ---------------------------------------------------------------------------
__global__ void transpose_w(const float* __restrict__ w, bf16_t* __restrict__ wt,
                            int K, int N)
{
    int i = blockIdx.x * 256 + threadIdx.x;
    if (i >= K * N) return;
    int k = i / N, n = i % N;
    wt[(long)n * K + k] = __float2bfloat16(w[i]);
}

// ---------------------------------------------------------------------------
// LN1 + shift + window gather: x(f32, global rows) -> xw(bf16, chunk-local)
// ---------------------------------------------------------------------------
__global__ __launch_bounds__(256) void ln1_kernel(const float* __restrict__ x,
                                                  const float* __restrict__ g,
                                                  const float* __restrict__ b,
                                                  bf16_t* __restrict__ xw,
                                                  int row_base)
{
    int t    = blockIdx.x * 4 + (threadIdx.x >> 6);    // chunk-local windowed token
    int lane = threadIdx.x & 63;
    long src = win_to_tok(row_base + t);
    const float* row = x + src * C_;
    float x0 = row[lane], x1 = row[lane + 64];
    float s = x0 + x1, q = x0 * x0 + x1 * x1;
#pragma unroll
    for (int off = 32; off; off >>= 1) {
        s += __shfl_xor(s, off);
        q += __shfl_xor(q, off);
    }
    float mean = s * (1.f / 128.f);
    float rstd = rsqrtf(q * (1.f / 128.f) - mean * mean + 1e-5f);
    bf16_t* orow = xw + (long)t * C_;
    orow[lane]      = __float2bfloat16((x0 - mean) * rstd * g[lane]      + b[lane]);
    orow[lane + 64] = __float2bfloat16((x1 - mean) * rstd * g[lane + 64] + b[lane + 64]);
}

// ---------------------------------------------------------------------------
// LN2: y(bf16, global rows) -> yln(bf16, chunk-local)
// ---------------------------------------------------------------------------
__global__ __launch_bounds__(256) void ln2_kernel(const bf16_t* __restrict__ y,
                                                  const float* __restrict__ g,
                                                  const float* __restrict__ b,
                                                  bf16_t* __restrict__ yln,
                                                  int row_base)
{
    int t    = blockIdx.x * 4 + (threadIdx.x >> 6);
    int lane = threadIdx.x & 63;
    const bf16_t* row = y + (long)(row_base + t) * C_;
    float x0 = __bfloat162float(row[lane]), x1 = __bfloat162float(row[lane + 64]);
    float s = x0 + x1, q = x0 * x0 + x1 * x1;
#pragma unroll
    for (int off = 32; off; off >>= 1) {
        s += __shfl_xor(s, off);
        q += __shfl_xor(q, off);
    }
    float mean = s * (1.f / 128.f);
    float rstd = rsqrtf(q * (1.f / 128.f) - mean * mean + 1e-5f);
    bf16_t* orow = yln + (long)t * C_;
    orow[lane]      = __float2bfloat16((x0 - mean) * rstd * g[lane]      + b[lane]);
    orow[lane + 64] = __float2bfloat16((x1 - mean) * rstd * g[lane + 64] + b[lane + 64]);
}

// ---------------------------------------------------------------------------
// GEMM, one wave = 64x64 output tile. Block = 4 waves stacked in M (256 rows).
// grid = (MCH/256, N/64). A: MCH x K bf16 row-major (chunk-local).
// Bt: N x K bf16. K=128: A/B fragments register-resident (32 indep loads,
// then 64 MFMAs). K=512: stream per-kt (4 B + 4 A loads per 16 MFMAs).
// EPI: 0 = store bf16 (qkv -> qkvb)
//      1 = window-reverse + unshift + x(f32) residual -> y bf16 global rows
//      2 = exact GELU -> bf16 (fc1 -> h1)
//      3 = + y(bf16) residual -> f32 d_out at global rows (fc2)
// ---------------------------------------------------------------------------
template<int K, int N, int EPI>
__global__ __launch_bounds__(256) void gemm2(const bf16_t* __restrict__ A,
                                             const bf16_t* __restrict__ Bt,
                                             const float*  __restrict__ bias,
                                             void*         __restrict__ outp,
                                             const float*  __restrict__ resx,
                                             const bf16_t* __restrict__ resy,
                                             int row_base)
{
    int lane = threadIdx.x & 63;
    int wave = threadIdx.x >> 6;
    int la = lane & 15, lb = lane >> 4;
    int slab = blockIdx.y;
    int m0   = (blockIdx.x * 4 + wave) * 64;        // chunk-local first row
    int c0   = slab * 64;                           // first col

    f32x4 acc[4][4];                                // [s(row sub)][nt(col sub)]
#pragma unroll
    for (int nt = 0; nt < 4; ++nt) {
        float bv = bias[c0 + nt * 16 + la];
#pragma unroll
        for (int s = 0; s < 4; ++s) acc[s][nt] = (f32x4){bv, bv, bv, bv};
    }

    if constexpr (K == 128) {
        bf16x8 breg[4][4];                          // [kt][nt]
#pragma unroll
        for (int kt = 0; kt < 4; ++kt)
#pragma unroll
            for (int nt = 0; nt < 4; ++nt)
                breg[kt][nt] = *reinterpret_cast<const bf16x8*>(
                    Bt + (long)(c0 + nt * 16 + la) * K + kt * 32 + lb * 8);
        bf16x8 areg[4][4];                          // [s][kt]
#pragma unroll
        for (int s = 0; s < 4; ++s)
#pragma unroll
            for (int kt = 0; kt < 4; ++kt)
                areg[s][kt] = *reinterpret_cast<const bf16x8*>(
                    A + (long)(m0 + s * 16 + la) * K + kt * 32 + lb * 8);
#pragma unroll
        for (int kt = 0; kt < 4; ++kt)
#pragma unroll
            for (int nt = 0; nt < 4; ++nt)
#pragma unroll
                for (int s = 0; s < 4; ++s)
                    acc[s][nt] = __builtin_amdgcn_mfma_f32_16x16x32_bf16(
                        areg[s][kt], breg[kt][nt], acc[s][nt], 0, 0, 0);
    } else {
#pragma unroll 4
        for (int kt = 0; kt < K / 32; ++kt) {
            bf16x8 b[4], a[4];
#pragma unroll
            for (int nt = 0; nt < 4; ++nt)
                b[nt] = *reinterpret_cast<const bf16x8*>(
                    Bt + (long)(c0 + nt * 16 + la) * K + kt * 32 + lb * 8);
#pragma unroll
            for (int s = 0; s < 4; ++s)
                a[s] = *reinterpret_cast<const bf16x8*>(
                    A + (long)(m0 + s * 16 + la) * K + kt * 32 + lb * 8);
#pragma unroll
            for (int nt = 0; nt < 4; ++nt)
#pragma unroll
                for (int s = 0; s < 4; ++s)
                    acc[s][nt] = __builtin_amdgcn_mfma_f32_16x16x32_bf16(
                        a[s], b[nt], acc[s][nt], 0, 0, 0);
        }
    }

    // ---- epilogue ----
#pragma unroll
    for (int s = 0; s < 4; ++s) {
#pragma unroll
        for (int r = 0; r < 4; ++r) {
            int row = m0 + s * 16 + lb * 4 + r;     // chunk-local
            if constexpr (EPI == 1) {
                long to = win_to_tok(row_base + row);
#pragma unroll
                for (int nt = 0; nt < 4; ++nt) {
                    int col = c0 + nt * 16 + la;
                    ((bf16_t*)outp)[to * C_ + col] =
                        __float2bfloat16(acc[s][nt][r] + resx[to * C_ + col]);
                }
            } else if constexpr (EPI == 3) {
                long gr = (long)(row_base + row);
#pragma unroll
                for (int nt = 0; nt < 4; ++nt) {
                    int col = c0 + nt * 16 + la;
                    ((float*)outp)[gr * N + col] =
                        acc[s][nt][r] + __bfloat162float(resy[gr * N + col]);
                }
            } else {
#pragma unroll
                for (int nt = 0; nt < 4; ++nt) {
                    int col = c0 + nt * 16 + la;
                    float v = acc[s][nt][r];
                    if constexpr (EPI == 2)
                        v = 0.5f * v * (1.f + erff(v * 0.70710678118654752f));
                    ((bf16_t*)outp)[(long)row * N + col] = __float2bfloat16(v);
                }
            }
        }
    }
}

// ---------------------------------------------------------------------------
// Windowed attention: one block per window, one wave per head.
// ---------------------------------------------------------------------------
__global__ __launch_bounds__(256) void attn_kernel(const bf16_t* __restrict__ qkv,
                                                   const float*  __restrict__ rpb,
                                                   bf16_t* __restrict__ out,
                                                   int win_base)
{
    int winl = blockIdx.x;
    int wing = win_base + winl;
    int h    = threadIdx.x >> 6;
    int lane = threadIdx.x & 63;

    __shared__ float kbuf[4][49][32];
    __shared__ float vbuf[4][49][32];

    const bf16_t* base = qkv + (long)winl * 49 * 384;

    for (int idx = lane; idx < 49 * 32; idx += 64) {
        int n = idx >> 5, d = idx & 31;
        kbuf[h][n][d] = __bfloat162float(base[n * 384 + 128 + h * 32 + d]);
        vbuf[h][n][d] = __bfloat162float(base[n * 384 + 256 + h * 32 + d]);
    }

    int n = lane < 49 ? lane : 48;
    f32x4 qv[8];
#pragma unroll
    for (int dq = 0; dq < 8; ++dq)
#pragma unroll
        for (int r = 0; r < 4; ++r)
            qv[dq][r] = __bfloat162float(base[n * 384 + h * 32 + dq * 4 + r]) *
                        0.17677669529663687f;   // 1/sqrt(32)

    __syncthreads();

    int wi  = wing & 63;
    int wh  = wi >> 3, wwp = wi & 7;
    int i1  = n / 7, j1 = n % 7;
    int hh1 = wh * 7 + i1, ww1 = wwp * 7 + j1;
    int rr1 = hh1 < 49 ? 0 : (hh1 < 53 ? 1 : 2);
    int rc1 = ww1 < 49 ? 0 : (ww1 < 53 ? 1 : 2);

    const f32x4* k4 = reinterpret_cast<const f32x4*>(&kbuf[h][0][0]);
    const f32x4* v4 = reinterpret_cast<const f32x4*>(&vbuf[h][0][0]);

    float S[49];
#pragma unroll
    for (int m = 0; m < 49; ++m) {
        f32x4 sv = (f32x4){0, 0, 0, 0};
#pragma unroll
        for (int dq = 0; dq < 8; ++dq)
            sv = k4[m * 8 + dq] * qv[dq] + sv;
        float s = sv[0] + sv[1] + sv[2] + sv[3];

        int i2 = m / 7, j2 = m % 7;
        s += rpb[((i1 - i2 + 6) * 13 + (j1 - j2 + 6)) * 4 + h];

        int hh2 = wh * 7 + i2, ww2 = wwp * 7 + j2;
        int rr2 = hh2 < 49 ? 0 : (hh2 < 53 ? 1 : 2);
        int rc2 = ww2 < 49 ? 0 : (ww2 < 53 ? 1 : 2);
        if (rr1 != rr2 || rc1 != rc2) s -= 100.f;
        S[m] = s;
    }

    float mx = -1e30f;
#pragma unroll
    for (int m = 0; m < 49; ++m) mx = fmaxf(mx, S[m]);
    float sum = 0.f;
#pragma unroll
    for (int m = 0; m < 49; ++m) { S[m] = __expf(S[m] - mx); sum += S[m]; }
    float inv = 1.f / sum;

    f32x4 o[8];
#pragma unroll
    for (int i = 0; i < 8; ++i) o[i] = (f32x4){0, 0, 0, 0};
#pragma unroll
    for (int m = 0; m < 49; ++m) {
        float pm = S[m] * inv;
#pragma unroll
        for (int dq = 0; dq < 8; ++dq)
            o[dq] = v4[m * 8 + dq] * pm + o[dq];
    }

    if (lane < 49) {
        bf16_t* orow = out + ((long)winl * 49 + lane) * C_ + h * 32;
#pragma unroll
        for (int dq = 0; dq < 8; ++dq)
#pragma unroll
            for (int r = 0; r < 4; ++r)
                orow[dq * 4 + r] = __float2bfloat16(o[dq][r]);
    }
}

// ---------------------------------------------------------------------------
extern "C" void kernel_launch(void* const* d_in, const int* in_sizes, int n_in,
                              void* d_out, int out_size, void* d_ws, size_t ws_size,
                              hipStream_t stream)
{
    (void)in_sizes; (void)n_in; (void)out_size;

    const float* x      = (const float*)d_in[0];
    const float* n1g    = (const float*)d_in[1];
    const float* n1b    = (const float*)d_in[2];
    const float* qkv_w  = (const float*)d_in[3];
    const float* qkv_b  = (const float*)d_in[4];
    const float* proj_w = (const float*)d_in[5];
    const float* proj_b = (const float*)d_in[6];
    const float* rpb    = (const float*)d_in[7];
    const float* n2g    = (const float*)d_in[8];
    const float* n2b    = (const float*)d_in[9];
    const float* fc1_w  = (const float*)d_in[10];
    const float* fc1_b  = (const float*)d_in[11];
    const float* fc2_w  = (const float*)d_in[12];
    const float* fc2_b  = (const float*)d_in[13];

    char*  ws  = (char*)d_ws;
    size_t off = 0;
    auto alloc = [&](size_t bytes) -> void* {
        void* p = ws + off;
        off += (bytes + 255) & ~(size_t)255;
        return p;
    };

    bf16_t* y        = (bf16_t*)alloc((size_t)M_ * C_ * 2);       // 51.4 MB
    char*   chunkbuf = (char*)  alloc((size_t)MCH * 512 * 2);     // 25.7 MB
    bf16_t* qkv_wt   = (bf16_t*)alloc(128 * 384 * 2);
    bf16_t* proj_wt  = (bf16_t*)alloc(128 * 128 * 2);
    bf16_t* fc1_wt   = (bf16_t*)alloc(128 * 512 * 2);
    bf16_t* fc2_wt   = (bf16_t*)alloc(512 * 128 * 2);

    if (off > ws_size) {
        sentinel_kernel<<<1, 256, 0, stream>>>((float*)d_out);
        return;
    }

    // attention-phase chunk buffers
    bf16_t* attb = (bf16_t*)chunkbuf;                              //  6.4 MB
    bf16_t* qkvb = (bf16_t*)(chunkbuf + (size_t)MCH * C_ * 2);     // 19.3 MB
    // MLP-phase chunk buffer
    bf16_t* h1   = (bf16_t*)chunkbuf;                              // 25.7 MB

    transpose_w<<<(128 * 384 + 255) / 256, 256, 0, stream>>>(qkv_w, qkv_wt, 128, 384);
    transpose_w<<<(128 * 128 + 255) / 256, 256, 0, stream>>>(proj_w, proj_wt, 128, 128);
    transpose_w<<<(128 * 512 + 255) / 256, 256, 0, stream>>>(fc1_w, fc1_wt, 128, 512);
    transpose_w<<<(512 * 128 + 255) / 256, 256, 0, stream>>>(fc2_w, fc2_wt, 512, 128);

    // ---- attention path, chunked ----
    for (int c = 0; c < NC; ++c) {
        int rb = c * MCH, wb = c * WCH;
        // xw scratch: y's chunk rows (dead until proj writes those same rows)
        bf16_t* xw = y + (size_t)rb * C_;
        ln1_kernel<<<MCH / 4, 256, 0, stream>>>(x, n1g, n1b, xw, rb);
        gemm2<128, 384, 0><<<dim3(MCH / 256, 6), 256, 0, stream>>>(
            xw, qkv_wt, qkv_b, qkvb, nullptr, nullptr, rb);
        attn_kernel<<<WCH, 256, 0, stream>>>(qkvb, rpb, attb, wb);
        gemm2<128, 128, 1><<<dim3(MCH / 256, 2), 256, 0, stream>>>(
            attb, proj_wt, proj_b, y, x, nullptr, rb);
    }

    // ---- MLP path, chunked ----
    for (int c = 0; c < NC; ++c) {
        int rb = c * MCH;
        // yln scratch: d_out's chunk region (dead until fc2 writes it)
        bf16_t* yln = (bf16_t*)((float*)d_out + (size_t)rb * C_);
        ln2_kernel<<<MCH / 4, 256, 0, stream>>>(y, n2g, n2b, yln, rb);
        gemm2<128, 512, 2><<<dim3(MCH / 256, 8), 256, 0, stream>>>(
            yln, fc1_wt, fc1_b, h1, nullptr, nullptr, rb);
        gemm2<512, 128, 3><<<dim3(MCH / 256, 2), 256, 0, stream>>>(
            h1, fc2_wt, fc2_b, d_out, nullptr, y, rb);
    }
}

// Round 4
// 943.831 us; speedup vs baseline: 1.4494x; 1.0273x over previous
//
#include <hip/hip_runtime.h>
#include <hip/hip_bf16.h>
#include <math.h>

typedef __bf16 bf16x8 __attribute__((ext_vector_type(8)));
typedef float  f32x4  __attribute__((ext_vector_type(4)));
typedef __hip_bfloat16 bf16_t;

static constexpr int C_    = 128;
static constexpr int L_    = 56 * 56;        // tokens per image
static constexpr int M_    = 64 * L_;        // 200704 total tokens
static constexpr int NWIN  = 64 * 64;        // 4096 windows

// map windowed token index tw -> unwindowed token index (shift+window bijection)
__device__ inline long win_to_tok(int tw)
{
    int win = tw / 49, n = tw % 49;
    int bb  = win >> 6, wi = win & 63;
    int wh  = wi >> 3, wwp = wi & 7;
    int hs  = wh * 7 + n / 7;
    int wsv = wwp * 7 + n % 7;
    int hh  = (hs + 3) % 56;          // un-shift
    int ww  = (wsv + 3) % 56;
    return (long)bb * L_ + hh * 56 + ww;
}

__global__ void sentinel_kernel(float* o) { o[threadIdx.x] = 1e9f; }

// ---------------------------------------------------------------------------
__global__ void transpose_w(const float* __restrict__ w, bf16_t* __restrict__ wt,
                            int K, int N)
{
    int i = blockIdx.x * 256 + threadIdx.x;
    if (i >= K * N) return;
    int k = i / N, n = i % N;
    wt[(long)n * K + k] = __float2bfloat16(w[i]);
}

// ---------------------------------------------------------------------------
// LN1 + shift + window gather: x(f32, global rows) -> xw(bf16, chunk-local)
// ---------------------------------------------------------------------------
__global__ __launch_bounds__(256) void ln1_kernel(const float* __restrict__ x,
                                                  const float* __restrict__ g,
                                                  const float* __restrict__ b,
                                                  bf16_t* __restrict__ xw,
                                                  int row_base)
{
    int t    = blockIdx.x * 4 + (threadIdx.x >> 6);    // chunk-local windowed token
    int lane = threadIdx.x & 63;
    long src = win_to_tok(row_base + t);
    const float* row = x + src * C_;
    float x0 = row[lane], x1 = row[lane + 64];
    float s = x0 + x1, q = x0 * x0 + x1 * x1;
#pragma unroll
    for (int off = 32; off; off >>= 1) {
        s += __shfl_xor(s, off);
        q += __shfl_xor(q, off);
    }
    float mean = s * (1.f / 128.f);
    float rstd = rsqrtf(q * (1.f / 128.f) - mean * mean + 1e-5f);
    bf16_t* orow = xw + (long)t * C_;
    orow[lane]      = __float2bfloat16((x0 - mean) * rstd * g[lane]      + b[lane]);
    orow[lane + 64] = __float2bfloat16((x1 - mean) * rstd * g[lane + 64] + b[lane + 64]);
}

// ---------------------------------------------------------------------------
// LN2: y(bf16, global rows) -> yln(bf16, chunk-local)
// ---------------------------------------------------------------------------
__global__ __launch_bounds__(256) void ln2_kernel(const bf16_t* __restrict__ y,
                                                  const float* __restrict__ g,
                                                  const float* __restrict__ b,
                                                  bf16_t* __restrict__ yln,
                                                  int row_base)
{
    int t    = blockIdx.x * 4 + (threadIdx.x >> 6);
    int lane = threadIdx.x & 63;
    const bf16_t* row = y + (long)(row_base + t) * C_;
    float x0 = __bfloat162float(row[lane]), x1 = __bfloat162float(row[lane + 64]);
    float s = x0 + x1, q = x0 * x0 + x1 * x1;
#pragma unroll
    for (int off = 32; off; off >>= 1) {
        s += __shfl_xor(s, off);
        q += __shfl_xor(q, off);
    }
    float mean = s * (1.f / 128.f);
    float rstd = rsqrtf(q * (1.f / 128.f) - mean * mean + 1e-5f);
    bf16_t* orow = yln + (long)t * C_;
    orow[lane]      = __float2bfloat16((x0 - mean) * rstd * g[lane]      + b[lane]);
    orow[lane + 64] = __float2bfloat16((x1 - mean) * rstd * g[lane + 64] + b[lane + 64]);
}

// ---------------------------------------------------------------------------
// GEMM, one wave = 64x64 output tile. Block = 4 waves stacked in M (256 rows).
// grid = (mch/256, N/64). A: mch x K bf16 row-major (chunk-local).
// EPI: 0 = store bf16 (qkv -> qkvb)
//      1 = window-reverse + unshift + x(f32) residual -> y bf16 global rows
//      2 = exact GELU -> bf16 (fc1 -> h1)
//      3 = + y(bf16) residual -> f32 d_out at global rows (fc2)
// ---------------------------------------------------------------------------
template<int K, int N, int EPI>
__global__ __launch_bounds__(256) void gemm2(const bf16_t* __restrict__ A,
                                             const bf16_t* __restrict__ Bt,
                                             const float*  __restrict__ bias,
                                             void*         __restrict__ outp,
                                             const float*  __restrict__ resx,
                                             const bf16_t* __restrict__ resy,
                                             int row_base)
{
    int lane = threadIdx.x & 63;
    int wave = threadIdx.x >> 6;
    int la = lane & 15, lb = lane >> 4;
    int slab = blockIdx.y;
    int m0   = (blockIdx.x * 4 + wave) * 64;        // chunk-local first row
    int c0   = slab * 64;                           // first col

    f32x4 acc[4][4];                                // [s(row sub)][nt(col sub)]
#pragma unroll
    for (int nt = 0; nt < 4; ++nt) {
        float bv = bias[c0 + nt * 16 + la];
#pragma unroll
        for (int s = 0; s < 4; ++s) acc[s][nt] = (f32x4){bv, bv, bv, bv};
    }

    if constexpr (K == 128) {
        bf16x8 breg[4][4];                          // [kt][nt]
#pragma unroll
        for (int kt = 0; kt < 4; ++kt)
#pragma unroll
            for (int nt = 0; nt < 4; ++nt)
                breg[kt][nt] = *reinterpret_cast<const bf16x8*>(
                    Bt + (long)(c0 + nt * 16 + la) * K + kt * 32 + lb * 8);
        bf16x8 areg[4][4];                          // [s][kt]
#pragma unroll
        for (int s = 0; s < 4; ++s)
#pragma unroll
            for (int kt = 0; kt < 4; ++kt)
                areg[s][kt] = *reinterpret_cast<const bf16x8*>(
                    A + (long)(m0 + s * 16 + la) * K + kt * 32 + lb * 8);
#pragma unroll
        for (int kt = 0; kt < 4; ++kt)
#pragma unroll
            for (int nt = 0; nt < 4; ++nt)
#pragma unroll
                for (int s = 0; s < 4; ++s)
                    acc[s][nt] = __builtin_amdgcn_mfma_f32_16x16x32_bf16(
                        areg[s][kt], breg[kt][nt], acc[s][nt], 0, 0, 0);
    } else {
#pragma unroll 4
        for (int kt = 0; kt < K / 32; ++kt) {
            bf16x8 b[4], a[4];
#pragma unroll
            for (int nt = 0; nt < 4; ++nt)
                b[nt] = *reinterpret_cast<const bf16x8*>(
                    Bt + (long)(c0 + nt * 16 + la) * K + kt * 32 + lb * 8);
#pragma unroll
            for (int s = 0; s < 4; ++s)
                a[s] = *reinterpret_cast<const bf16x8*>(
                    A + (long)(m0 + s * 16 + la) * K + kt * 32 + lb * 8);
#pragma unroll
            for (int nt = 0; nt < 4; ++nt)
#pragma unroll
                for (int s = 0; s < 4; ++s)
                    acc[s][nt] = __builtin_amdgcn_mfma_f32_16x16x32_bf16(
                        a[s], b[nt], acc[s][nt], 0, 0, 0);
        }
    }

    // ---- epilogue ----
#pragma unroll
    for (int s = 0; s < 4; ++s) {
#pragma unroll
        for (int r = 0; r < 4; ++r) {
            int row = m0 + s * 16 + lb * 4 + r;     // chunk-local
            if constexpr (EPI == 1) {
                long to = win_to_tok(row_base + row);
#pragma unroll
                for (int nt = 0; nt < 4; ++nt) {
                    int col = c0 + nt * 16 + la;
                    ((bf16_t*)outp)[to * C_ + col] =
                        __float2bfloat16(acc[s][nt][r] + resx[to * C_ + col]);
                }
            } else if constexpr (EPI == 3) {
                long gr = (long)(row_base + row);
#pragma unroll
                for (int nt = 0; nt < 4; ++nt) {
                    int col = c0 + nt * 16 + la;
                    ((float*)outp)[gr * N + col] =
                        acc[s][nt][r] + __bfloat162float(resy[gr * N + col]);
                }
            } else {
#pragma unroll
                for (int nt = 0; nt < 4; ++nt) {
                    int col = c0 + nt * 16 + la;
                    float v = acc[s][nt][r];
                    if constexpr (EPI == 2)
                        v = 0.5f * v * (1.f + erff(v * 0.70710678118654752f));
                    ((bf16_t*)outp)[(long)row * N + col] = __float2bfloat16(v);
                }
            }
        }
    }
}

// ---------------------------------------------------------------------------
// Windowed attention v2: one block per window, one wave per head.
// K,V staged in LDS as bf16 (25 KB/block), vectorized 16B staging loads.
// Lane n (<49) owns query row n entirely in registers.
// ---------------------------------------------------------------------------
__global__ __launch_bounds__(256) void attn_kernel(const bf16_t* __restrict__ qkv,
                                                   const float*  __restrict__ rpb,
                                                   bf16_t* __restrict__ out,
                                                   int win_base)
{
    int winl = blockIdx.x;
    int wing = win_base + winl;
    int h    = threadIdx.x >> 6;
    int lane = threadIdx.x & 63;

    __shared__ __bf16 kbuf[4][49][32];
    __shared__ __bf16 vbuf[4][49][32];

    const bf16_t* base = qkv + (long)winl * 49 * 384;
    const bf16_t* kh = base + 128 + h * 32;
    const bf16_t* vh = base + 256 + h * 32;

    // stage K,V: 49 rows x 4 bf16x8 each
    for (int idx = lane; idx < 196; idx += 64) {
        int n8 = idx >> 2, d8 = (idx & 3) * 8;
        *reinterpret_cast<bf16x8*>(&kbuf[h][n8][d8]) =
            *reinterpret_cast<const bf16x8*>(kh + (long)n8 * 384 + d8);
        *reinterpret_cast<bf16x8*>(&vbuf[h][n8][d8]) =
            *reinterpret_cast<const bf16x8*>(vh + (long)n8 * 384 + d8);
    }

    int n = lane < 49 ? lane : 48;
    const bf16_t* qh = base + (long)n * 384 + h * 32;
    f32x4 qv[8];
#pragma unroll
    for (int t = 0; t < 4; ++t) {
        bf16x8 q8 = *reinterpret_cast<const bf16x8*>(qh + t * 8);
#pragma unroll
        for (int j = 0; j < 8; ++j)
            qv[t * 2 + (j >> 2)][j & 3] = (float)q8[j] * 0.17677669529663687f;
    }

    __syncthreads();

    int wi  = wing & 63;
    int wh  = wi >> 3, wwp = wi & 7;
    int i1  = n / 7, j1 = n % 7;
    int hh1 = wh * 7 + i1, ww1 = wwp * 7 + j1;
    int rr1 = hh1 < 49 ? 0 : (hh1 < 53 ? 1 : 2);
    int rc1 = ww1 < 49 ? 0 : (ww1 < 53 ? 1 : 2);

    const bf16x8* k8 = reinterpret_cast<const bf16x8*>(&kbuf[h][0][0]);
    const bf16x8* v8 = reinterpret_cast<const bf16x8*>(&vbuf[h][0][0]);

    float S[49];
#pragma unroll
    for (int m = 0; m < 49; ++m) {
        f32x4 sv = (f32x4){0, 0, 0, 0};
#pragma unroll
        for (int t = 0; t < 4; ++t) {
            bf16x8 kv = k8[m * 4 + t];
            f32x4 lo = {(float)kv[0], (float)kv[1], (float)kv[2], (float)kv[3]};
            f32x4 hi = {(float)kv[4], (float)kv[5], (float)kv[6], (float)kv[7]};
            sv = lo * qv[t * 2]     + sv;
            sv = hi * qv[t * 2 + 1] + sv;
        }
        float s = sv[0] + sv[1] + sv[2] + sv[3];

        int i2 = m / 7, j2 = m % 7;
        s += rpb[((i1 - i2 + 6) * 13 + (j1 - j2 + 6)) * 4 + h];

        int hh2 = wh * 7 + i2, ww2 = wwp * 7 + j2;
        int rr2 = hh2 < 49 ? 0 : (hh2 < 53 ? 1 : 2);
        int rc2 = ww2 < 49 ? 0 : (ww2 < 53 ? 1 : 2);
        if (rr1 != rr2 || rc1 != rc2) s -= 100.f;
        S[m] = s;
    }

    float mx = -1e30f;
#pragma unroll
    for (int m = 0; m < 49; ++m) mx = fmaxf(mx, S[m]);
    float sum = 0.f;
#pragma unroll
    for (int m = 0; m < 49; ++m) { S[m] = __expf(S[m] - mx); sum += S[m]; }
    float inv = 1.f / sum;

    f32x4 o[8];
#pragma unroll
    for (int i = 0; i < 8; ++i) o[i] = (f32x4){0, 0, 0, 0};
#pragma unroll
    for (int m = 0; m < 49; ++m) {
        float pm = S[m] * inv;
#pragma unroll
        for (int t = 0; t < 4; ++t) {
            bf16x8 vv = v8[m * 4 + t];
            f32x4 lo = {(float)vv[0], (float)vv[1], (float)vv[2], (float)vv[3]};
            f32x4 hi = {(float)vv[4], (float)vv[5], (float)vv[6], (float)vv[7]};
            o[t * 2]     = lo * pm + o[t * 2];
            o[t * 2 + 1] = hi * pm + o[t * 2 + 1];
        }
    }

    if (lane < 49) {
        bf16_t* orow = out + ((long)winl * 49 + lane) * C_ + h * 32;
#pragma unroll
        for (int t = 0; t < 4; ++t) {
            bf16x8 ov;
#pragma unroll
            for (int j = 0; j < 8; ++j)
                ov[j] = (__bf16)o[t * 2 + (j >> 2)][j & 3];
            *reinterpret_cast<bf16x8*>(orow + t * 8) = ov;
        }
    }
}

// ---------------------------------------------------------------------------
extern "C" void kernel_launch(void* const* d_in, const int* in_sizes, int n_in,
                              void* d_out, int out_size, void* d_ws, size_t ws_size,
                              hipStream_t stream)
{
    (void)in_sizes; (void)n_in; (void)out_size;

    const float* x      = (const float*)d_in[0];
    const float* n1g    = (const float*)d_in[1];
    const float* n1b    = (const float*)d_in[2];
    const float* qkv_w  = (const float*)d_in[3];
    const float* qkv_b  = (const float*)d_in[4];
    const float* proj_w = (const float*)d_in[5];
    const float* proj_b = (const float*)d_in[6];
    const float* rpb    = (const float*)d_in[7];
    const float* n2g    = (const float*)d_in[8];
    const float* n2b    = (const float*)d_in[9];
    const float* fc1_w  = (const float*)d_in[10];
    const float* fc1_b  = (const float*)d_in[11];
    const float* fc2_w  = (const float*)d_in[12];
    const float* fc2_b  = (const float*)d_in[13];

    // choose the fewest chunks that fit the workspace (deterministic in ws_size)
    int nc = 8;
    {
        const size_t fixed = (size_t)M_ * C_ * 2 + 4 * 131072;   // y + weights upper bound
        for (int cand : {1, 2, 4, 8})
            if (fixed + (size_t)(M_ / cand) * 512 * 2 <= ws_size) { nc = cand; break; }
    }
    const int mch = M_ / nc;        // rows per chunk
    const int wch = NWIN / nc;      // windows per chunk

    char*  ws  = (char*)d_ws;
    size_t off = 0;
    auto alloc = [&](size_t bytes) -> void* {
        void* p = ws + off;
        off += (bytes + 255) & ~(size_t)255;
        return p;
    };

    bf16_t* y        = (bf16_t*)alloc((size_t)M_ * C_ * 2);
    char*   chunkbuf = (char*)  alloc((size_t)mch * 512 * 2);
    bf16_t* qkv_wt   = (bf16_t*)alloc(128 * 384 * 2);
    bf16_t* proj_wt  = (bf16_t*)alloc(128 * 128 * 2);
    bf16_t* fc1_wt   = (bf16_t*)alloc(128 * 512 * 2);
    bf16_t* fc2_wt   = (bf16_t*)alloc(512 * 128 * 2);

    if (off > ws_size) {
        sentinel_kernel<<<1, 256, 0, stream>>>((float*)d_out);
        return;
    }

    // attention-phase chunk buffers
    bf16_t* attb = (bf16_t*)chunkbuf;                              // mch*128*2
    bf16_t* qkvb = (bf16_t*)(chunkbuf + (size_t)mch * C_ * 2);     // mch*384*2
    // MLP-phase chunk buffer
    bf16_t* h1   = (bf16_t*)chunkbuf;                              // mch*512*2

    transpose_w<<<(128 * 384 + 255) / 256, 256, 0, stream>>>(qkv_w, qkv_wt, 128, 384);
    transpose_w<<<(128 * 128 + 255) / 256, 256, 0, stream>>>(proj_w, proj_wt, 128, 128);
    transpose_w<<<(128 * 512 + 255) / 256, 256, 0, stream>>>(fc1_w, fc1_wt, 128, 512);
    transpose_w<<<(512 * 128 + 255) / 256, 256, 0, stream>>>(fc2_w, fc2_wt, 512, 128);

    // ---- attention path, chunked ----
    for (int c = 0; c < nc; ++c) {
        int rb = c * mch, wb = c * wch;
        // xw scratch: y's chunk rows (dead until proj writes those same rows)
        bf16_t* xw = y + (size_t)rb * C_;
        ln1_kernel<<<mch / 4, 256, 0, stream>>>(x, n1g, n1b, xw, rb);
        gemm2<128, 384, 0><<<dim3(mch / 256, 6), 256, 0, stream>>>(
            xw, qkv_wt, qkv_b, qkvb, nullptr, nullptr, rb);
        attn_kernel<<<wch, 256, 0, stream>>>(qkvb, rpb, attb, wb);
        gemm2<128, 128, 1><<<dim3(mch / 256, 2), 256, 0, stream>>>(
            attb, proj_wt, proj_b, y, x, nullptr, rb);
    }

    // ---- MLP path, chunked ----
    for (int c = 0; c < nc; ++c) {
        int rb = c * mch;
        // yln scratch: d_out's chunk region (dead until fc2 writes it)
        bf16_t* yln = (bf16_t*)((float*)d_out + (size_t)rb * C_);
        ln2_kernel<<<mch / 4, 256, 0, stream>>>(y, n2g, n2b, yln, rb);
        gemm2<128, 512, 2><<<dim3(mch / 256, 8), 256, 0, stream>>>(
            yln, fc1_wt, fc1_b, h1, nullptr, nullptr, rb);
        gemm2<512, 128, 3><<<dim3(mch / 256, 2), 256, 0, stream>>>(
            h1, fc2_wt, fc2_b, d_out, nullptr, y, rb);
    }
}

// Round 5
// 793.032 us; speedup vs baseline: 1.7250x; 1.1902x over previous
//
#include <hip/hip_runtime.h>
#include <hip/hip_bf16.h>
#include <math.h>

typedef __bf16 bf16x8 __attribute__((ext_vector_type(8)));
typedef float  f32x4  __attribute__((ext_vector_type(4)));
typedef unsigned int u32x4 __attribute__((ext_vector_type(4)));
typedef __hip_bfloat16 bf16_t;

static constexpr int C_    = 128;
static constexpr int L_    = 56 * 56;        // tokens per image
static constexpr int M_    = 64 * L_;        // 200704 total tokens
static constexpr int NWIN  = 64 * 64;        // 4096 windows
static constexpr int VSTR  = 56;             // vT padded key stride (16B-aligned rows)

// map windowed token index tw -> unwindowed token index (shift+window bijection)
__device__ inline long win_to_tok(int tw)
{
    int win = tw / 49, n = tw % 49;
    int bb  = win >> 6, wi = win & 63;
    int wh  = wi >> 3, wwp = wi & 7;
    int hs  = wh * 7 + n / 7;
    int wsv = wwp * 7 + n % 7;
    int hh  = (hs + 3) % 56;          // un-shift
    int ww  = (wsv + 3) % 56;
    return (long)bb * L_ + hh * 56 + ww;
}

__device__ inline unsigned int pk2(float lo, float hi)
{
    unsigned short a = __builtin_bit_cast(unsigned short, (__bf16)lo);
    unsigned short b = __builtin_bit_cast(unsigned short, (__bf16)hi);
    return (unsigned int)a | ((unsigned int)b << 16);
}

__global__ void sentinel_kernel(float* o) { o[threadIdx.x] = 1e9f; }

// ---------------------------------------------------------------------------
__global__ void transpose_w(const float* __restrict__ w, bf16_t* __restrict__ wt,
                            int K, int N)
{
    int i = blockIdx.x * 256 + threadIdx.x;
    if (i >= K * N) return;
    int k = i / N, n = i % N;
    wt[(long)n * K + k] = __float2bfloat16(w[i]);
}

// zero vT pad keys 49..55 for all (win, d)
__global__ void zpad_kernel(bf16_t* __restrict__ vT)
{
    long i = (long)blockIdx.x * 256 + threadIdx.x;
    if (i >= (long)NWIN * 128 * 7) return;
    long row = i / 7;
    int  k   = 49 + (int)(i % 7);
    vT[row * VSTR + k] = __float2bfloat16(0.f);
}

// ---------------------------------------------------------------------------
// LN1 + shift + window gather: x(f32) -> xw(bf16, windowed token order)
// ---------------------------------------------------------------------------
__global__ __launch_bounds__(256) void ln1_kernel(const float* __restrict__ x,
                                                  const float* __restrict__ g,
                                                  const float* __restrict__ b,
                                                  bf16_t* __restrict__ xw)
{
    int t    = blockIdx.x * 4 + (threadIdx.x >> 6);
    int lane = threadIdx.x & 63;
    long src = win_to_tok(t);
    const float* row = x + src * C_;
    float x0 = row[lane], x1 = row[lane + 64];
    float s = x0 + x1, q = x0 * x0 + x1 * x1;
#pragma unroll
    for (int off = 32; off; off >>= 1) {
        s += __shfl_xor(s, off);
        q += __shfl_xor(q, off);
    }
    float mean = s * (1.f / 128.f);
    float rstd = rsqrtf(q * (1.f / 128.f) - mean * mean + 1e-5f);
    bf16_t* orow = xw + (long)t * C_;
    orow[lane]      = __float2bfloat16((x0 - mean) * rstd * g[lane]      + b[lane]);
    orow[lane + 64] = __float2bfloat16((x1 - mean) * rstd * g[lane + 64] + b[lane + 64]);
}

// ---------------------------------------------------------------------------
// LN2: y (f32, = d_out) -> yln (bf16)
// ---------------------------------------------------------------------------
__global__ __launch_bounds__(256) void ln2f_kernel(const float* __restrict__ y,
                                                   const float* __restrict__ g,
                                                   const float* __restrict__ b,
                                                   bf16_t* __restrict__ yln)
{
    int t    = blockIdx.x * 4 + (threadIdx.x >> 6);
    int lane = threadIdx.x & 63;
    const float* row = y + (long)t * C_;
    float x0 = row[lane], x1 = row[lane + 64];
    float s = x0 + x1, q = x0 * x0 + x1 * x1;
#pragma unroll
    for (int off = 32; off; off >>= 1) {
        s += __shfl_xor(s, off);
        q += __shfl_xor(q, off);
    }
    float mean = s * (1.f / 128.f);
    float rstd = rsqrtf(q * (1.f / 128.f) - mean * mean + 1e-5f);
    bf16_t* orow = yln + (long)t * C_;
    orow[lane]      = __float2bfloat16((x0 - mean) * rstd * g[lane]      + b[lane]);
    orow[lane + 64] = __float2bfloat16((x1 - mean) * rstd * g[lane + 64] + b[lane + 64]);
}

// ---------------------------------------------------------------------------
// GEMM, one wave = 64x64 output tile. Block = 4 waves stacked in M (256 rows).
// grid = (M/256, N/64). A: M x K bf16 row-major. Bt: N x K bf16.
// EPI: 0 = qkv: cols<256 -> qk[token][256]; cols>=256 -> vT[win][d][key] (transposed V)
//      1 = proj: window-reverse + unshift + x(f32) residual -> f32 d_out
//      2 = fc1: exact GELU -> bf16 h1
//      3 = fc2: + resf(f32) -> f32 out at same rows (in-place ok)
// ---------------------------------------------------------------------------
template<int K, int N, int EPI>
__global__ __launch_bounds__(256) void gemm2(const bf16_t* __restrict__ A,
                                             const bf16_t* __restrict__ Bt,
                                             const float*  __restrict__ bias,
                                             void*         outp,
                                             const float*  resf,
                                             bf16_t*       vTp)
{
    int lane = threadIdx.x & 63;
    int wave = threadIdx.x >> 6;
    int la = lane & 15, lb = lane >> 4;
    int m0   = (blockIdx.x * 4 + wave) * 64;
    int c0   = blockIdx.y * 64;

    f32x4 acc[4][4];
#pragma unroll
    for (int nt = 0; nt < 4; ++nt) {
        float bv = bias[c0 + nt * 16 + la];
#pragma unroll
        for (int s = 0; s < 4; ++s) acc[s][nt] = (f32x4){bv, bv, bv, bv};
    }

    if constexpr (K == 128) {
        bf16x8 breg[4][4];
#pragma unroll
        for (int kt = 0; kt < 4; ++kt)
#pragma unroll
            for (int nt = 0; nt < 4; ++nt)
                breg[kt][nt] = *reinterpret_cast<const bf16x8*>(
                    Bt + (long)(c0 + nt * 16 + la) * K + kt * 32 + lb * 8);
        bf16x8 areg[4][4];
#pragma unroll
        for (int s = 0; s < 4; ++s)
#pragma unroll
            for (int kt = 0; kt < 4; ++kt)
                areg[s][kt] = *reinterpret_cast<const bf16x8*>(
                    A + (long)(m0 + s * 16 + la) * K + kt * 32 + lb * 8);
#pragma unroll
        for (int kt = 0; kt < 4; ++kt)
#pragma unroll
            for (int nt = 0; nt < 4; ++nt)
#pragma unroll
                for (int s = 0; s < 4; ++s)
                    acc[s][nt] = __builtin_amdgcn_mfma_f32_16x16x32_bf16(
                        areg[s][kt], breg[kt][nt], acc[s][nt], 0, 0, 0);
    } else {
#pragma unroll 4
        for (int kt = 0; kt < K / 32; ++kt) {
            bf16x8 b[4], a[4];
#pragma unroll
            for (int nt = 0; nt < 4; ++nt)
                b[nt] = *reinterpret_cast<const bf16x8*>(
                    Bt + (long)(c0 + nt * 16 + la) * K + kt * 32 + lb * 8);
#pragma unroll
            for (int s = 0; s < 4; ++s)
                a[s] = *reinterpret_cast<const bf16x8*>(
                    A + (long)(m0 + s * 16 + la) * K + kt * 32 + lb * 8);
#pragma unroll
            for (int nt = 0; nt < 4; ++nt)
#pragma unroll
                for (int s = 0; s < 4; ++s)
                    acc[s][nt] = __builtin_amdgcn_mfma_f32_16x16x32_bf16(
                        a[s], b[nt], acc[s][nt], 0, 0, 0);
        }
    }

#pragma unroll
    for (int s = 0; s < 4; ++s) {
#pragma unroll
        for (int r = 0; r < 4; ++r) {
            int row = m0 + s * 16 + lb * 4 + r;
            if constexpr (EPI == 0) {
                int win = row / 49, key = row - win * 49;
#pragma unroll
                for (int nt = 0; nt < 4; ++nt) {
                    int col = c0 + nt * 16 + la;
                    float v = acc[s][nt][r];
                    if (col < 256)
                        ((bf16_t*)outp)[(long)row * 256 + col] = __float2bfloat16(v);
                    else
                        vTp[((long)win * 128 + (col - 256)) * VSTR + key] = __float2bfloat16(v);
                }
            } else if constexpr (EPI == 1) {
                long to = win_to_tok(row);
#pragma unroll
                for (int nt = 0; nt < 4; ++nt) {
                    int col = c0 + nt * 16 + la;
                    ((float*)outp)[to * C_ + col] = acc[s][nt][r] + resf[to * C_ + col];
                }
            } else if constexpr (EPI == 3) {
#pragma unroll
                for (int nt = 0; nt < 4; ++nt) {
                    int col = c0 + nt * 16 + la;
                    ((float*)outp)[(long)row * N + col] =
                        acc[s][nt][r] + resf[(long)row * N + col];
                }
            } else {
#pragma unroll
                for (int nt = 0; nt < 4; ++nt) {
                    int col = c0 + nt * 16 + la;
                    float v = acc[s][nt][r];
                    v = 0.5f * v * (1.f + erff(v * 0.70710678118654752f));
                    ((bf16_t*)outp)[(long)row * N + col] = __float2bfloat16(v);
                }
            }
        }
    }
}

// ---------------------------------------------------------------------------
// MFMA windowed attention: one block per window, one wave per head. No LDS.
// S^T tiles: S[key][q] = mfma(A=K rows, B=Q cols). Softmax over keys =
// in-lane (kt,r) + shfl over lb. P repacked to PV B-frags via in-register
// shfl. V read pre-transposed (vT[win][d][key]). Out C[d][q] -> attb.
// ---------------------------------------------------------------------------
__global__ __launch_bounds__(256) void attn_mfma(const bf16_t* __restrict__ qk,
                                                 const bf16_t* __restrict__ vT,
                                                 const float*  __restrict__ rpb,
                                                 bf16_t* __restrict__ out)
{
    int win  = blockIdx.x;
    int h    = threadIdx.x >> 6;
    int lane = threadIdx.x & 63;
    int la = lane & 15, lb = lane >> 4;

    const bf16_t* qkw = qk + (long)win * 49 * 256;

    // fragments straight from global (L2/L3-resident)
    bf16x8 kf[4], qf[4];
#pragma unroll
    for (int t = 0; t < 4; ++t) {
        kf[t] = *reinterpret_cast<const bf16x8*>(qkw + (long)(t * 16 + la) * 256 + 128 + h * 32 + lb * 8);
        qf[t] = *reinterpret_cast<const bf16x8*>(qkw + (long)(t * 16 + la) * 256 +       h * 32 + lb * 8);
    }

    // S^T tiles: S[qt][kt], lane holds S[key=kt*16+lb*4+r][q=qt*16+la]
    f32x4 S[4][4];
#pragma unroll
    for (int qt = 0; qt < 4; ++qt)
#pragma unroll
        for (int kt = 0; kt < 4; ++kt)
            S[qt][kt] = __builtin_amdgcn_mfma_f32_16x16x32_bf16(
                kf[kt], qf[qt], (f32x4){0.f, 0.f, 0.f, 0.f}, 0, 0, 0);

    // ---- bias + shift-mask ----
    const float scale = 0.17677669529663687f;   // 1/sqrt(32)
    int wi  = win & 63;
    int wh  = wi >> 3, wwp = wi & 7;
    bool edge = (wh == 7) || (wwp == 7);

    int i1[4], j1[4], r1[4], c1[4];
#pragma unroll
    for (int qt = 0; qt < 4; ++qt) {
        int q  = qt * 16 + la;
        int qc = q < 49 ? q : 48;
        i1[qt] = qc / 7; j1[qt] = qc - 7 * i1[qt];
        r1[qt] = (wh  < 7) ? 0 : ((i1[qt] < 4) ? 1 : 2);
        c1[qt] = (wwp < 7) ? 0 : ((j1[qt] < 4) ? 1 : 2);
    }

#pragma unroll
    for (int kt = 0; kt < 4; ++kt) {
#pragma unroll
        for (int r = 0; r < 4; ++r) {
            if (kt == 3 && r > 0) {            // key = 48+lb*4+r >= 49 always
#pragma unroll
                for (int qt = 0; qt < 4; ++qt) S[qt][kt][r] = -1e30f;
                continue;
            }
            int key = kt * 16 + lb * 4 + r;
            int kc  = key < 49 ? key : 48;
            int i2  = kc / 7, j2 = kc - 7 * i2;
            int r2  = (wh  < 7) ? 0 : ((i2 < 4) ? 1 : 2);
            int c2  = (wwp < 7) ? 0 : ((j2 < 4) ? 1 : 2);
#pragma unroll
            for (int qt = 0; qt < 4; ++qt) {
                float bv  = rpb[(((i1[qt] - i2 + 6) * 13 + (j1[qt] - j2 + 6)) << 2) + h];
                float val = S[qt][kt][r] * scale + bv;
                if (edge && ((r1[qt] != r2) | (c1[qt] != c2))) val -= 100.f;
                if (kt == 3 && lb > 0) val = -1e30f;   // key = 48+lb*4 >= 49
                S[qt][kt][r] = val;
            }
        }
    }

    // ---- softmax over keys (unnormalized E; 1/sum folded into store) ----
    float inv[4];
#pragma unroll
    for (int qt = 0; qt < 4; ++qt) {
        float mx = -3e38f;
#pragma unroll
        for (int kt = 0; kt < 4; ++kt)
#pragma unroll
            for (int r = 0; r < 4; ++r) mx = fmaxf(mx, S[qt][kt][r]);
        mx = fmaxf(mx, __shfl_xor(mx, 16));
        mx = fmaxf(mx, __shfl_xor(mx, 32));
        float sm = 0.f;
#pragma unroll
        for (int kt = 0; kt < 4; ++kt)
#pragma unroll
            for (int r = 0; r < 4; ++r) {
                float e = __expf(S[qt][kt][r] - mx);
                S[qt][kt][r] = e;
                sm += e;
            }
        sm += __shfl_xor(sm, 16);
        sm += __shfl_xor(sm, 32);
        inv[qt] = 1.f / sm;
    }

    // ---- pack E to bf16 pairs: w[qt][t][rr] covers keys t*16+lb*4+2rr..+1 ----
    unsigned int w_[4][4][2];
#pragma unroll
    for (int qt = 0; qt < 4; ++qt)
#pragma unroll
        for (int t = 0; t < 4; ++t) {
            w_[qt][t][0] = pk2(S[qt][t][0], S[qt][t][1]);
            w_[qt][t][1] = pk2(S[qt][t][2], S[qt][t][3]);
        }

    // ---- PV: O[dt][qt] += mfma(V^T frag, P^T frag) ----
    int srcA = la + (((2 * lb)     & 3) << 4);
    int srcB = la + (((2 * lb + 1) & 3) << 4);
    bool hiT = (lb >> 1) & 1;

    f32x4 O[2][4];
#pragma unroll
    for (int dt = 0; dt < 2; ++dt)
#pragma unroll
        for (int qt = 0; qt < 4; ++qt) O[dt][qt] = (f32x4){0.f, 0.f, 0.f, 0.f};

    const bf16_t* vrow = vT + ((long)win * 128 + h * 32) * VSTR;
#pragma unroll
    for (int kk = 0; kk < 2; ++kk) {
        bf16x8 vf[2];
#pragma unroll
        for (int dt = 0; dt < 2; ++dt)
            vf[dt] = *reinterpret_cast<const bf16x8*>(
                vrow + (long)(dt * 16 + la) * VSTR + kk * 32 + lb * 8);
        int tl = kk * 2;
#pragma unroll
        for (int qt = 0; qt < 4; ++qt) {
            unsigned int a0 = __shfl(w_[qt][tl][0],     srcA);
            unsigned int b0 = __shfl(w_[qt][tl + 1][0], srcA);
            unsigned int a1 = __shfl(w_[qt][tl][1],     srcA);
            unsigned int b1 = __shfl(w_[qt][tl + 1][1], srcA);
            unsigned int a2 = __shfl(w_[qt][tl][0],     srcB);
            unsigned int b2 = __shfl(w_[qt][tl + 1][0], srcB);
            unsigned int a3 = __shfl(w_[qt][tl][1],     srcB);
            unsigned int b3 = __shfl(w_[qt][tl + 1][1], srcB);
            u32x4 uu = { hiT ? b0 : a0, hiT ? b1 : a1, hiT ? b2 : a2, hiT ? b3 : a3 };
            bf16x8 pf = __builtin_bit_cast(bf16x8, uu);
#pragma unroll
            for (int dt = 0; dt < 2; ++dt)
                O[dt][qt] = __builtin_amdgcn_mfma_f32_16x16x32_bf16(vf[dt], pf, O[dt][qt], 0, 0, 0);
        }
    }

    // ---- store: lane holds out[d = dt*16+lb*4+r][q = qt*16+la] ----
    bf16_t* ob = out + (long)win * 49 * C_ + h * 32;
#pragma unroll
    for (int qt = 0; qt < 4; ++qt) {
        int q = qt * 16 + la;
        if (q < 49) {
            float iv = inv[qt];
#pragma unroll
            for (int dt = 0; dt < 2; ++dt) {
                unsigned int s0 = pk2(O[dt][qt][0] * iv, O[dt][qt][1] * iv);
                unsigned int s1 = pk2(O[dt][qt][2] * iv, O[dt][qt][3] * iv);
                uint2 st = {s0, s1};
                *reinterpret_cast<uint2*>(ob + (long)q * C_ + dt * 16 + lb * 4) = st;
            }
        }
    }
}

// ---------------------------------------------------------------------------
extern "C" void kernel_launch(void* const* d_in, const int* in_sizes, int n_in,
                              void* d_out, int out_size, void* d_ws, size_t ws_size,
                              hipStream_t stream)
{
    (void)in_sizes; (void)n_in; (void)out_size;

    const float* x      = (const float*)d_in[0];
    const float* n1g    = (const float*)d_in[1];
    const float* n1b    = (const float*)d_in[2];
    const float* qkv_w  = (const float*)d_in[3];
    const float* qkv_b  = (const float*)d_in[4];
    const float* proj_w = (const float*)d_in[5];
    const float* proj_b = (const float*)d_in[6];
    const float* rpb    = (const float*)d_in[7];
    const float* n2g    = (const float*)d_in[8];
    const float* n2b    = (const float*)d_in[9];
    const float* fc1_w  = (const float*)d_in[10];
    const float* fc1_b  = (const float*)d_in[11];
    const float* fc2_w  = (const float*)d_in[12];
    const float* fc2_b  = (const float*)d_in[13];

    char* ws = (char*)d_ws;

    // attention phase:  [qk | vT | attb(=xw)]
    const size_t qk_sz = (size_t)M_ * 256 * 2;               // 102,760,448
    const size_t vt_sz = (size_t)NWIN * 128 * VSTR * 2;      //  58,720,256
    const size_t at_sz = (size_t)M_ * 128 * 2;               //  51,380,224
    // MLP phase:        [yln | h1]
    const size_t h1_sz = (size_t)M_ * 512 * 2;               // 205,520,896
    const size_t w_off = at_sz + h1_sz;                      // 256,901,120
    const size_t w_sz  = (size_t)(128 * 384 + 128 * 128 + 128 * 512 + 512 * 128) * 2;
    const size_t need  = w_off + w_sz;                       // 257,294,336

    if (need > ws_size) {
        sentinel_kernel<<<1, 256, 0, stream>>>((float*)d_out);
        return;
    }

    bf16_t* qkb  = (bf16_t*)ws;
    bf16_t* vT   = (bf16_t*)(ws + qk_sz);
    bf16_t* attb = (bf16_t*)(ws + qk_sz + vt_sz);   // also xw before attention
    bf16_t* yln  = (bf16_t*)ws;
    bf16_t* h1   = (bf16_t*)(ws + at_sz);
    bf16_t* qkv_wt  = (bf16_t*)(ws + w_off);
    bf16_t* proj_wt = qkv_wt + 128 * 384;
    bf16_t* fc1_wt  = proj_wt + 128 * 128;
    bf16_t* fc2_wt  = fc1_wt + 128 * 512;

    bf16_t* xw = attb;
    float*  y  = (float*)d_out;

    transpose_w<<<(128 * 384 + 255) / 256, 256, 0, stream>>>(qkv_w, qkv_wt, 128, 384);
    transpose_w<<<(128 * 128 + 255) / 256, 256, 0, stream>>>(proj_w, proj_wt, 128, 128);
    transpose_w<<<(128 * 512 + 255) / 256, 256, 0, stream>>>(fc1_w, fc1_wt, 128, 512);
    transpose_w<<<(512 * 128 + 255) / 256, 256, 0, stream>>>(fc2_w, fc2_wt, 512, 128);

    // LN1 + shift + window partition
    ln1_kernel<<<M_ / 4, 256, 0, stream>>>(x, n1g, n1b, xw);
    // zero vT pad keys (NaN safety for PV fragments)
    zpad_kernel<<<(NWIN * 128 * 7 + 255) / 256, 256, 0, stream>>>(vT);
    // QKV projection: Q,K row-major + V transposed per window
    gemm2<128, 384, 0><<<dim3(M_ / 256, 6), 256, 0, stream>>>(
        xw, qkv_wt, qkv_b, qkb, nullptr, vT);
    // MFMA attention (overwrites xw region with attb)
    attn_mfma<<<NWIN, 256, 0, stream>>>(qkb, vT, rpb, attb);
    // proj + window-reverse + x residual -> f32 y (= d_out)
    gemm2<128, 128, 1><<<dim3(M_ / 256, 2), 256, 0, stream>>>(
        attb, proj_wt, proj_b, y, x, nullptr);
    // LN2
    ln2f_kernel<<<M_ / 4, 256, 0, stream>>>(y, n2g, n2b, yln);
    // fc1 + exact GELU
    gemm2<128, 512, 2><<<dim3(M_ / 256, 8), 256, 0, stream>>>(
        yln, fc1_wt, fc1_b, h1, nullptr, nullptr);
    // fc2 + residual (in-place on d_out)
    gemm2<512, 128, 3><<<dim3(M_ / 256, 2), 256, 0, stream>>>(
        h1, fc2_wt, fc2_b, y, y, nullptr);
}